// Round 1
// baseline (42878.922 us; speedup 1.0000x reference)
//
#include <hip/hip_runtime.h>

#define T_STEPS 2048
#define BATCH   256
#define HID     512
#define NG      16   // gate-slice blocks per batch group (h-cols 512/NG = 32 each)
#define NB      16   // batch groups (rows 256/NB = 16 each)

typedef _Float16 half8 __attribute__((ext_vector_type(8)));
typedef _Float16 half2v __attribute__((ext_vector_type(2)));
typedef float f32x4 __attribute__((ext_vector_type(4)));

__device__ __forceinline__ float sigmoid_f(float v) {
    return 1.f / (1.f + __expf(-v));
}
__device__ __forceinline__ float tanh_f(float v) {
    float a = fabsf(v);
    float e = __expf(2.f * a);
    float r = 1.f - 2.f / (e + 1.f);
    return copysignf(r, v);
}

// grid = 256 blocks (g = blockIdx&15 batch group, j = blockIdx>>4 gate slice)
// block = 256 threads = 4 waves; wave w owns gate type w (i,f,g,o), cols 0..31 of slice
__global__ __launch_bounds__(256) void lstm_persistent(
    const float* __restrict__ x,     // (T,B)
    const float* __restrict__ Wih,   // (4H,1)
    const float* __restrict__ Whh,   // (4H,H)
    const float* __restrict__ bih,   // (4H)
    const float* __restrict__ bhh,   // (4H)
    const float* __restrict__ Wlin,  // (1,H)
    _Float16* __restrict__ hbuf,     // [2][B][H] fp16
    unsigned*  __restrict__ flags,   // [NB][T][NG]
    float* __restrict__ partial)     // [NG][B]
{
    const int tid  = threadIdx.x;
    const int g    = blockIdx.x & 15;   // batch group
    const int j    = blockIdx.x >> 4;   // gate slice
    const int wave = tid >> 6;          // gate type 0..3
    const int lane = tid & 63;
    const int quad = lane >> 4;
    const int ln16 = lane & 15;

    __shared__ float lds_gates[4][16][32];
    __shared__ float lds_wx[4][32];
    __shared__ float lds_bias[4][32];

    // ---- stationary weights: fp16 MFMA B-fragments in registers ----
    // B[k][n] = Whh[gate_row(n)][k]; lane holds n=ln16, k = quad*8 + e (+32*ks)
    half8 bf0[16], bf1[16];
    {
        const float* wr0 = Whh + (size_t)(wave * 512 + j * 32 + ln16) * HID;
        const float* wr1 = Whh + (size_t)(wave * 512 + j * 32 + 16 + ln16) * HID;
        #pragma unroll
        for (int ks = 0; ks < 16; ++ks) {
            int k0 = ks * 32 + quad * 8;
            half8 v0, v1;
            #pragma unroll
            for (int e = 0; e < 8; ++e) {
                v0[e] = (_Float16)wr0[k0 + e];
                v1[e] = (_Float16)wr1[k0 + e];
            }
            bf0[ks] = v0;
            bf1[ks] = v1;
        }
    }
    if (tid < 128) {
        int gt = tid >> 5, c = tid & 31;
        int grow = gt * 512 + j * 32 + c;
        lds_wx[gt][c]   = Wih[grow];
        lds_bias[gt][c] = bih[grow] + bhh[grow];
    }
    __syncthreads();

    const int row_e = tid >> 4;          // epilogue row 0..15
    const int cp    = (tid & 15) * 2;    // epilogue col pair 0,2,..,30
    float c0 = 0.f, c1 = 0.f;            // cell state (fp32, register-resident)
    float hl0 = 0.f, hl1 = 0.f;          // last h values (fp32)
    bool  dead = false;                  // sticky bailout (avoid unbounded hang)

    for (int t = 0; t < T_STEPS; ++t) {
        // ---- wait for peers' h of step t-1 (every wave spins -> per-wave acquire) ----
        if (t > 0 && !dead) {
            unsigned* fl = flags + ((size_t)g * T_STEPS + (t - 1)) * NG + (lane & 15);
            unsigned it = 0;
            while (__hip_atomic_load(fl, __ATOMIC_ACQUIRE, __HIP_MEMORY_SCOPE_AGENT) == 0u) {
                if (++it > 2000000u) { dead = true; break; }
            }
        }

        // ---- gates tile: A (16x512 fp16 from global) x B(regs) -> 16x32 (this wave's gate) ----
        const _Float16* ha = hbuf + (size_t)(t & 1) * (BATCH * HID)
                                  + (size_t)(g * 16 + ln16) * HID + quad * 8;
        f32x4 acc0 = {0.f, 0.f, 0.f, 0.f};
        f32x4 acc1 = {0.f, 0.f, 0.f, 0.f};
        #pragma unroll
        for (int ks = 0; ks < 16; ++ks) {
            half8 af = *(const half8*)(ha + ks * 32);
            acc0 = __builtin_amdgcn_mfma_f32_16x16x32_f16(af, bf0[ks], acc0, 0, 0, 0);
            acc1 = __builtin_amdgcn_mfma_f32_16x16x32_f16(af, bf1[ks], acc1, 0, 0, 0);
        }
        // C layout: col = ln16, row = quad*4 + r
        #pragma unroll
        for (int r = 0; r < 4; ++r) {
            lds_gates[wave][quad * 4 + r][ln16]      = acc0[r];
            lds_gates[wave][quad * 4 + r][16 + ln16] = acc1[r];
        }
        __syncthreads();

        // ---- epilogue: thread -> (row_e, cols cp,cp+1); c in regs; h -> global fp16 ----
        const float xin = x[(size_t)t * BATCH + g * 16 + row_e];
        float hv0, hv1;
        {
            float gi = lds_gates[0][row_e][cp]     + xin * lds_wx[0][cp]     + lds_bias[0][cp];
            float gf = lds_gates[1][row_e][cp]     + xin * lds_wx[1][cp]     + lds_bias[1][cp];
            float gg = lds_gates[2][row_e][cp]     + xin * lds_wx[2][cp]     + lds_bias[2][cp];
            float go = lds_gates[3][row_e][cp]     + xin * lds_wx[3][cp]     + lds_bias[3][cp];
            float iv = sigmoid_f(gi), fv = sigmoid_f(gf), gv = tanh_f(gg), ov = sigmoid_f(go);
            c0 = fv * c0 + iv * gv;
            hv0 = ov * tanh_f(c0);
        }
        {
            float gi = lds_gates[0][row_e][cp + 1] + xin * lds_wx[0][cp + 1] + lds_bias[0][cp + 1];
            float gf = lds_gates[1][row_e][cp + 1] + xin * lds_wx[1][cp + 1] + lds_bias[1][cp + 1];
            float gg = lds_gates[2][row_e][cp + 1] + xin * lds_wx[2][cp + 1] + lds_bias[2][cp + 1];
            float go = lds_gates[3][row_e][cp + 1] + xin * lds_wx[3][cp + 1] + lds_bias[3][cp + 1];
            float iv = sigmoid_f(gi), fv = sigmoid_f(gf), gv = tanh_f(gg), ov = sigmoid_f(go);
            c1 = fv * c1 + iv * gv;
            hv1 = ov * tanh_f(c1);
        }
        hl0 = hv0; hl1 = hv1;
        half2v hh;
        hh[0] = (_Float16)hv0;
        hh[1] = (_Float16)hv1;
        *(half2v*)(hbuf + (size_t)((t + 1) & 1) * (BATCH * HID)
                        + (size_t)(g * 16 + row_e) * HID + j * 32 + cp) = hh;

        __syncthreads();  // all h stores drained (vmcnt) before publishing
        if (tid == 0) {
            __hip_atomic_store(flags + ((size_t)g * T_STEPS + t) * NG + j, 1u,
                               __ATOMIC_RELEASE, __HIP_MEMORY_SCOPE_AGENT);
        }
        // NOTE: no barrier at loop top needed: the pre-flag __syncthreads already
        // guarantees all waves finished reading lds_gates before next step's writes.
    }

    // ---- partial output: sum over this block's 32 h-cols per row ----
    float p = hl0 * Wlin[j * 32 + cp] + hl1 * Wlin[j * 32 + cp + 1];
    #pragma unroll
    for (int off = 8; off; off >>= 1) p += __shfl_down(p, off, 16);
    if ((tid & 15) == 0) partial[(size_t)j * BATCH + g * 16 + row_e] = p;
}

__global__ void lstm_finalize(const float* __restrict__ partial,
                              const float* __restrict__ blin,
                              float* __restrict__ out)
{
    int b = threadIdx.x;
    float s = blin[0];
    #pragma unroll
    for (int j = 0; j < NG; ++j) s += partial[(size_t)j * BATCH + b];
    out[b] = s;
}

extern "C" void kernel_launch(void* const* d_in, const int* in_sizes, int n_in,
                              void* d_out, int out_size, void* d_ws, size_t ws_size,
                              hipStream_t stream) {
    const float* x    = (const float*)d_in[0];
    const float* Wih  = (const float*)d_in[1];
    const float* Whh  = (const float*)d_in[2];
    const float* bih  = (const float*)d_in[3];
    const float* bhh  = (const float*)d_in[4];
    const float* Wlin = (const float*)d_in[5];
    const float* blin = (const float*)d_in[6];

    char* ws = (char*)d_ws;
    _Float16* hbuf   = (_Float16*)ws;                                  // 2*256*512*2 = 512 KB
    unsigned* flags  = (unsigned*)(ws + (512 << 10));                  // 16*2048*16*4 = 2 MB
    float*    partial = (float*)(ws + (512 << 10) + (2 << 20));        // 16 KB

    // zero h(t=-1) buffer (buf0) and all step flags (ws is poisoned each launch)
    hipMemsetAsync(hbuf, 0, (size_t)BATCH * HID * sizeof(_Float16), stream);
    hipMemsetAsync(flags, 0, (size_t)NB * T_STEPS * NG * sizeof(unsigned), stream);

    lstm_persistent<<<dim3(256), dim3(256), 0, stream>>>(
        x, Wih, Whh, bih, bhh, Wlin, hbuf, flags, partial);
    lstm_finalize<<<dim3(1), dim3(256), 0, stream>>>(partial, blin, (float*)d_out);
}

// Round 2
// 29236.072 us; speedup vs baseline: 1.4666x; 1.4666x over previous
//
#include <hip/hip_runtime.h>

#define T_STEPS 2048
#define BATCH   256
#define HID     512
#define NG      16   // gate-slice blocks per batch group (h-cols 512/NG = 32 each)
#define NB      16   // batch groups (rows 256/NB = 16 each)

typedef _Float16 half8 __attribute__((ext_vector_type(8)));
typedef _Float16 half2v __attribute__((ext_vector_type(2)));
typedef float f32x4 __attribute__((ext_vector_type(4)));

__device__ __forceinline__ float sigmoid_f(float v) {
    return 1.f / (1.f + __expf(-v));
}
__device__ __forceinline__ float tanh_f(float v) {
    float a = fabsf(v);
    float e = __expf(2.f * a);
    float r = 1.f - 2.f / (e + 1.f);
    return copysignf(r, v);
}

// grid = 256 blocks (g = blockIdx&15 batch group, j = blockIdx>>4 gate slice)
// block = 256 threads = 4 waves; wave w owns gate type w (i,f,g,o), cols 0..31 of slice
__global__ __launch_bounds__(256) void lstm_persistent(
    const float* __restrict__ x,     // (T,B)
    const float* __restrict__ Wih,   // (4H,1)
    const float* __restrict__ Whh,   // (4H,H)
    const float* __restrict__ bih,   // (4H)
    const float* __restrict__ bhh,   // (4H)
    const float* __restrict__ Wlin,  // (1,H)
    _Float16* __restrict__ hbuf,     // [2][B][H] fp16
    unsigned*  __restrict__ flags,   // [NB][T][NG]
    float* __restrict__ partial)     // [NG][B]
{
    const int tid  = threadIdx.x;
    const int g    = blockIdx.x & 15;   // batch group
    const int j    = blockIdx.x >> 4;   // gate slice
    const int wave = tid >> 6;          // gate type 0..3
    const int lane = tid & 63;
    const int quad = lane >> 4;
    const int ln16 = lane & 15;

    __shared__ float lds_gates[4][16][32];
    __shared__ float lds_wx[4][32];
    __shared__ float lds_bias[4][32];

    // ---- stationary weights: fp16 MFMA B-fragments in registers ----
    // B[k][n] = Whh[gate_row(n)][k]; lane holds n=ln16, k = quad*8 + e (+32*ks)
    half8 bf0[16], bf1[16];
    {
        const float* wr0 = Whh + (size_t)(wave * 512 + j * 32 + ln16) * HID;
        const float* wr1 = Whh + (size_t)(wave * 512 + j * 32 + 16 + ln16) * HID;
        #pragma unroll
        for (int ks = 0; ks < 16; ++ks) {
            int k0 = ks * 32 + quad * 8;
            half8 v0, v1;
            #pragma unroll
            for (int e = 0; e < 8; ++e) {
                v0[e] = (_Float16)wr0[k0 + e];
                v1[e] = (_Float16)wr1[k0 + e];
            }
            bf0[ks] = v0;
            bf1[ks] = v1;
        }
    }
    if (tid < 128) {
        int gt = tid >> 5, c = tid & 31;
        int grow = gt * 512 + j * 32 + c;
        lds_wx[gt][c]   = Wih[grow];
        lds_bias[gt][c] = bih[grow] + bhh[grow];
    }
    __syncthreads();

    const int row_e = tid >> 4;          // epilogue row 0..15
    const int cp    = (tid & 15) * 2;    // epilogue col pair 0,2,..,30
    float c0 = 0.f, c1 = 0.f;            // cell state (fp32, register-resident)
    float hl0 = 0.f, hl1 = 0.f;          // last h values (fp32)
    bool  dead = false;                  // sticky bailout (avoid unbounded hang)

    for (int t = 0; t < T_STEPS; ++t) {
        // ---- wait for peers' h of step t-1 ----
        // RELAXED polls (no cache invalidate per iteration; load goes to the
        // coherence point), completion detected via ballot, then ONE acquire
        // fence per wave (single buffer_inv) before reading peer h.
        if (t > 0 && !dead) {
            const unsigned* fl = flags + ((size_t)g * T_STEPS + (t - 1)) * NG + ln16;
            unsigned it = 0;
            for (;;) {
                unsigned v = __hip_atomic_load(fl, __ATOMIC_RELAXED, __HIP_MEMORY_SCOPE_AGENT);
                if (__ballot(v != 0u) == ~0ull) break;
                if (++it > 4000000u) { dead = true; break; }
            }
            __builtin_amdgcn_fence(__ATOMIC_ACQUIRE, "agent");
        }

        // ---- gates tile: A (16x512 fp16 from global) x B(regs) -> 16x32 (this wave's gate) ----
        const _Float16* ha = hbuf + (size_t)(t & 1) * (BATCH * HID)
                                  + (size_t)(g * 16 + ln16) * HID + quad * 8;
        f32x4 acc0 = {0.f, 0.f, 0.f, 0.f};
        f32x4 acc1 = {0.f, 0.f, 0.f, 0.f};
        #pragma unroll
        for (int ks = 0; ks < 16; ++ks) {
            half8 af = *(const half8*)(ha + ks * 32);
            acc0 = __builtin_amdgcn_mfma_f32_16x16x32_f16(af, bf0[ks], acc0, 0, 0, 0);
            acc1 = __builtin_amdgcn_mfma_f32_16x16x32_f16(af, bf1[ks], acc1, 0, 0, 0);
        }
        // C layout: col = ln16, row = quad*4 + r
        #pragma unroll
        for (int r = 0; r < 4; ++r) {
            lds_gates[wave][quad * 4 + r][ln16]      = acc0[r];
            lds_gates[wave][quad * 4 + r][16 + ln16] = acc1[r];
        }
        __syncthreads();

        // ---- epilogue: thread -> (row_e, cols cp,cp+1); c in regs; h -> global fp16 ----
        const float xin = x[(size_t)t * BATCH + g * 16 + row_e];
        float hv0, hv1;
        {
            float gi = lds_gates[0][row_e][cp]     + xin * lds_wx[0][cp]     + lds_bias[0][cp];
            float gf = lds_gates[1][row_e][cp]     + xin * lds_wx[1][cp]     + lds_bias[1][cp];
            float gg = lds_gates[2][row_e][cp]     + xin * lds_wx[2][cp]     + lds_bias[2][cp];
            float go = lds_gates[3][row_e][cp]     + xin * lds_wx[3][cp]     + lds_bias[3][cp];
            float iv = sigmoid_f(gi), fv = sigmoid_f(gf), gv = tanh_f(gg), ov = sigmoid_f(go);
            c0 = fv * c0 + iv * gv;
            hv0 = ov * tanh_f(c0);
        }
        {
            float gi = lds_gates[0][row_e][cp + 1] + xin * lds_wx[0][cp + 1] + lds_bias[0][cp + 1];
            float gf = lds_gates[1][row_e][cp + 1] + xin * lds_wx[1][cp + 1] + lds_bias[1][cp + 1];
            float gg = lds_gates[2][row_e][cp + 1] + xin * lds_wx[2][cp + 1] + lds_bias[2][cp + 1];
            float go = lds_gates[3][row_e][cp + 1] + xin * lds_wx[3][cp + 1] + lds_bias[3][cp + 1];
            float iv = sigmoid_f(gi), fv = sigmoid_f(gf), gv = tanh_f(gg), ov = sigmoid_f(go);
            c1 = fv * c1 + iv * gv;
            hv1 = ov * tanh_f(c1);
        }
        hl0 = hv0; hl1 = hv1;
        half2v hh;
        hh[0] = (_Float16)hv0;
        hh[1] = (_Float16)hv1;
        // nontemporal: push h toward the coherence point; keeps the release's
        // L2 writeback nearly empty.
        __builtin_nontemporal_store(hh,
            (half2v*)(hbuf + (size_t)((t + 1) & 1) * (BATCH * HID)
                           + (size_t)(g * 16 + row_e) * HID + j * 32 + cp));

        __syncthreads();  // drains vmcnt in every wave -> all h stores complete
        if (tid == 0) {
            __hip_atomic_store(flags + ((size_t)g * T_STEPS + t) * NG + j, 1u,
                               __ATOMIC_RELEASE, __HIP_MEMORY_SCOPE_AGENT);
        }
    }

    // ---- partial output: sum over this block's 32 h-cols per row ----
    float p = hl0 * Wlin[j * 32 + cp] + hl1 * Wlin[j * 32 + cp + 1];
    #pragma unroll
    for (int off = 8; off; off >>= 1) p += __shfl_down(p, off, 16);
    if ((tid & 15) == 0) partial[(size_t)j * BATCH + g * 16 + row_e] = p;
}

__global__ void lstm_finalize(const float* __restrict__ partial,
                              const float* __restrict__ blin,
                              float* __restrict__ out)
{
    int b = threadIdx.x;
    float s = blin[0];
    #pragma unroll
    for (int j = 0; j < NG; ++j) s += partial[(size_t)j * BATCH + b];
    out[b] = s;
}

extern "C" void kernel_launch(void* const* d_in, const int* in_sizes, int n_in,
                              void* d_out, int out_size, void* d_ws, size_t ws_size,
                              hipStream_t stream) {
    const float* x    = (const float*)d_in[0];
    const float* Wih  = (const float*)d_in[1];
    const float* Whh  = (const float*)d_in[2];
    const float* bih  = (const float*)d_in[3];
    const float* bhh  = (const float*)d_in[4];
    const float* Wlin = (const float*)d_in[5];
    const float* blin = (const float*)d_in[6];

    char* ws = (char*)d_ws;
    _Float16* hbuf   = (_Float16*)ws;                                  // 2*256*512*2 = 512 KB
    unsigned* flags  = (unsigned*)(ws + (512 << 10));                  // 16*2048*16*4 = 2 MB
    float*    partial = (float*)(ws + (512 << 10) + (2 << 20));        // 16 KB

    // zero h(t=-1) buffer (buf0) and all step flags (ws is poisoned each launch)
    hipMemsetAsync(hbuf, 0, (size_t)BATCH * HID * sizeof(_Float16), stream);
    hipMemsetAsync(flags, 0, (size_t)NB * T_STEPS * NG * sizeof(unsigned), stream);

    lstm_persistent<<<dim3(256), dim3(256), 0, stream>>>(
        x, Wih, Whh, bih, bhh, Wlin, hbuf, flags, partial);
    lstm_finalize<<<dim3(1), dim3(256), 0, stream>>>(partial, blin, (float*)d_out);
}

// Round 3
// 17831.024 us; speedup vs baseline: 2.4047x; 1.6396x over previous
//
#include <hip/hip_runtime.h>

#define T_STEPS 2048
#define BATCH   256
#define HID     512
#define NG      16   // gate-slice blocks per batch group (h-cols 512/NG = 32 each)
#define NB      16   // batch groups (rows 256/NB = 16 each)

typedef _Float16 half8 __attribute__((ext_vector_type(8)));
typedef _Float16 half2v __attribute__((ext_vector_type(2)));
typedef float f32x4 __attribute__((ext_vector_type(4)));
typedef int int4v __attribute__((ext_vector_type(4)));

__device__ __forceinline__ float sigmoid_f(float v) {
    return 1.f / (1.f + __expf(-v));
}
__device__ __forceinline__ float tanh_f(float v) {
    float a = fabsf(v);
    float e = __expf(2.f * a);
    float r = 1.f - 2.f / (e + 1.f);
    return copysignf(r, v);
}

// grid = 256 blocks (g = blockIdx&15 batch group, j = blockIdx>>4 gate slice)
// block = 256 threads = 4 waves; wave w owns gate type w (i,f,g,o), cols 0..31 of slice
// Sync protocol: ALL cross-block data (h, flags) moves via relaxed agent-scope
// atomics (sc1 -> bypass L1/L2, coherent at MALL). No acquire-inv / release-wbl2
// cache maintenance anywhere in the loop.
__global__ __launch_bounds__(256, 1) void lstm_persistent(
    const float* __restrict__ x,     // (T,B)
    const float* __restrict__ Wih,   // (4H,1)
    const float* __restrict__ Whh,   // (4H,H)
    const float* __restrict__ bih,   // (4H)
    const float* __restrict__ bhh,   // (4H)
    const float* __restrict__ Wlin,  // (1,H)
    _Float16* __restrict__ hbuf,     // [2][B][H] fp16
    unsigned*  __restrict__ flags,   // [NB][T][NG]
    float* __restrict__ partial)     // [NG][B]
{
    const int tid  = threadIdx.x;
    const int g    = blockIdx.x & 15;   // batch group
    const int j    = blockIdx.x >> 4;   // gate slice
    const int wave = tid >> 6;          // gate type 0..3
    const int lane = tid & 63;
    const int quad = lane >> 4;
    const int ln16 = lane & 15;

    __shared__ float lds_gates[4][16][32];
    __shared__ float lds_wx[4][32];
    __shared__ float lds_bias[4][32];

    // ---- stationary weights: fp16 MFMA B-fragments in registers ----
    // B[k][n] = Whh[gate_row(n)][k]; lane holds n=ln16, k = quad*8 + e (+32*ks)
    half8 bf0[16], bf1[16];
    {
        const float* wr0 = Whh + (size_t)(wave * 512 + j * 32 + ln16) * HID;
        const float* wr1 = Whh + (size_t)(wave * 512 + j * 32 + 16 + ln16) * HID;
        #pragma unroll
        for (int ks = 0; ks < 16; ++ks) {
            int k0 = ks * 32 + quad * 8;
            half8 v0, v1;
            #pragma unroll
            for (int e = 0; e < 8; ++e) {
                v0[e] = (_Float16)wr0[k0 + e];
                v1[e] = (_Float16)wr1[k0 + e];
            }
            bf0[ks] = v0;
            bf1[ks] = v1;
        }
    }
    if (tid < 128) {
        int gt = tid >> 5, c = tid & 31;
        int grow = gt * 512 + j * 32 + c;
        lds_wx[gt][c]   = Wih[grow];
        lds_bias[gt][c] = bih[grow] + bhh[grow];
    }
    __syncthreads();

    const int row_e = tid >> 4;          // epilogue row 0..15
    const int cp    = (tid & 15) * 2;    // epilogue col pair 0,2,..,30
    float c0 = 0.f, c1 = 0.f;            // cell state (fp32, register-resident)
    float hl0 = 0.f, hl1 = 0.f;          // last h values (fp32)
    bool  dead = false;                  // sticky bailout (avoid unbounded hang)

    for (int t = 0; t < T_STEPS; ++t) {
        // ---- wait for peers' h of step t-1: relaxed agent polls, no fence ----
        if (t > 0 && !dead) {
            const unsigned* fl = flags + ((size_t)g * T_STEPS + (t - 1)) * NG + ln16;
            unsigned it = 0;
            for (;;) {
                unsigned v = __hip_atomic_load(fl, __ATOMIC_RELAXED, __HIP_MEMORY_SCOPE_AGENT);
                if (__ballot(v != 0u) == ~0ull) break;
                if (++it > 4000000u) { dead = true; break; }
            }
        }

        // ---- gates tile: A (16x512 fp16, agent-scope loads) x B(regs) -> 16x32 ----
        const unsigned* ha4 = (const unsigned*)(hbuf
            + (size_t)(t & 1) * (BATCH * HID)
            + (size_t)(g * 16 + ln16) * HID + quad * 8);
        f32x4 a0e = {0.f,0.f,0.f,0.f}, a0o = {0.f,0.f,0.f,0.f};
        f32x4 a1e = {0.f,0.f,0.f,0.f}, a1o = {0.f,0.f,0.f,0.f};
        #pragma unroll
        for (int ks = 0; ks < 16; ++ks) {
            const unsigned* p = ha4 + ks * 16;   // ks*32 halves
            int4v iv;
            iv[0] = (int)__hip_atomic_load(p + 0, __ATOMIC_RELAXED, __HIP_MEMORY_SCOPE_AGENT);
            iv[1] = (int)__hip_atomic_load(p + 1, __ATOMIC_RELAXED, __HIP_MEMORY_SCOPE_AGENT);
            iv[2] = (int)__hip_atomic_load(p + 2, __ATOMIC_RELAXED, __HIP_MEMORY_SCOPE_AGENT);
            iv[3] = (int)__hip_atomic_load(p + 3, __ATOMIC_RELAXED, __HIP_MEMORY_SCOPE_AGENT);
            half8 af = __builtin_bit_cast(half8, iv);
            if (ks & 1) {
                a0o = __builtin_amdgcn_mfma_f32_16x16x32_f16(af, bf0[ks], a0o, 0, 0, 0);
                a1o = __builtin_amdgcn_mfma_f32_16x16x32_f16(af, bf1[ks], a1o, 0, 0, 0);
            } else {
                a0e = __builtin_amdgcn_mfma_f32_16x16x32_f16(af, bf0[ks], a0e, 0, 0, 0);
                a1e = __builtin_amdgcn_mfma_f32_16x16x32_f16(af, bf1[ks], a1e, 0, 0, 0);
            }
        }
        f32x4 acc0 = a0e + a0o;
        f32x4 acc1 = a1e + a1o;
        // C layout: col = ln16, row = quad*4 + r
        #pragma unroll
        for (int r = 0; r < 4; ++r) {
            lds_gates[wave][quad * 4 + r][ln16]      = acc0[r];
            lds_gates[wave][quad * 4 + r][16 + ln16] = acc1[r];
        }
        __syncthreads();

        // ---- epilogue: thread -> (row_e, cols cp,cp+1); c in regs; h -> global fp16 ----
        const float xin = x[(size_t)t * BATCH + g * 16 + row_e];
        float hv0, hv1;
        {
            float gi = lds_gates[0][row_e][cp]     + xin * lds_wx[0][cp]     + lds_bias[0][cp];
            float gf = lds_gates[1][row_e][cp]     + xin * lds_wx[1][cp]     + lds_bias[1][cp];
            float gg = lds_gates[2][row_e][cp]     + xin * lds_wx[2][cp]     + lds_bias[2][cp];
            float go = lds_gates[3][row_e][cp]     + xin * lds_wx[3][cp]     + lds_bias[3][cp];
            float iv = sigmoid_f(gi), fv = sigmoid_f(gf), gv = tanh_f(gg), ov = sigmoid_f(go);
            c0 = fv * c0 + iv * gv;
            hv0 = ov * tanh_f(c0);
        }
        {
            float gi = lds_gates[0][row_e][cp + 1] + xin * lds_wx[0][cp + 1] + lds_bias[0][cp + 1];
            float gf = lds_gates[1][row_e][cp + 1] + xin * lds_wx[1][cp + 1] + lds_bias[1][cp + 1];
            float gg = lds_gates[2][row_e][cp + 1] + xin * lds_wx[2][cp + 1] + lds_bias[2][cp + 1];
            float go = lds_gates[3][row_e][cp + 1] + xin * lds_wx[3][cp + 1] + lds_bias[3][cp + 1];
            float iv = sigmoid_f(gi), fv = sigmoid_f(gf), gv = tanh_f(gg), ov = sigmoid_f(go);
            c1 = fv * c1 + iv * gv;
            hv1 = ov * tanh_f(c1);
        }
        hl0 = hv0; hl1 = hv1;
        half2v hh;
        hh[0] = (_Float16)hv0;
        hh[1] = (_Float16)hv1;
        unsigned hbits = __builtin_bit_cast(unsigned, hh);
        // agent-scope store: goes to the coherence point, never dirty in L2
        __hip_atomic_store(
            (unsigned*)(hbuf + (size_t)((t + 1) & 1) * (BATCH * HID)
                             + (size_t)(g * 16 + row_e) * HID + j * 32 + cp),
            hbits, __ATOMIC_RELAXED, __HIP_MEMORY_SCOPE_AGENT);

        __syncthreads();  // s_waitcnt vmcnt(0): all agent-scope h stores are at MALL
        if (tid == 0) {
            __hip_atomic_store(flags + ((size_t)g * T_STEPS + t) * NG + j, 1u,
                               __ATOMIC_RELAXED, __HIP_MEMORY_SCOPE_AGENT);
        }
    }

    // ---- partial output: sum over this block's 32 h-cols per row ----
    float p = hl0 * Wlin[j * 32 + cp] + hl1 * Wlin[j * 32 + cp + 1];
    #pragma unroll
    for (int off = 8; off; off >>= 1) p += __shfl_down(p, off, 16);
    if ((tid & 15) == 0) partial[(size_t)j * BATCH + g * 16 + row_e] = p;
}

__global__ void lstm_finalize(const float* __restrict__ partial,
                              const float* __restrict__ blin,
                              float* __restrict__ out)
{
    int b = threadIdx.x;
    float s = blin[0];
    #pragma unroll
    for (int j = 0; j < NG; ++j) s += partial[(size_t)j * BATCH + b];
    out[b] = s;
}

extern "C" void kernel_launch(void* const* d_in, const int* in_sizes, int n_in,
                              void* d_out, int out_size, void* d_ws, size_t ws_size,
                              hipStream_t stream) {
    const float* x    = (const float*)d_in[0];
    const float* Wih  = (const float*)d_in[1];
    const float* Whh  = (const float*)d_in[2];
    const float* bih  = (const float*)d_in[3];
    const float* bhh  = (const float*)d_in[4];
    const float* Wlin = (const float*)d_in[5];
    const float* blin = (const float*)d_in[6];

    char* ws = (char*)d_ws;
    _Float16* hbuf   = (_Float16*)ws;                                  // 2*256*512*2 = 512 KB
    unsigned* flags  = (unsigned*)(ws + (512 << 10));                  // 16*2048*16*4 = 2 MB
    float*    partial = (float*)(ws + (512 << 10) + (2 << 20));        // 16 KB

    // zero h(t=-1) buffer (buf0) and all step flags (ws is poisoned each launch)
    hipMemsetAsync(hbuf, 0, (size_t)BATCH * HID * sizeof(_Float16), stream);
    hipMemsetAsync(flags, 0, (size_t)NB * T_STEPS * NG * sizeof(unsigned), stream);

    lstm_persistent<<<dim3(256), dim3(256), 0, stream>>>(
        x, Wih, Whh, bih, bhh, Wlin, hbuf, flags, partial);
    lstm_finalize<<<dim3(1), dim3(256), 0, stream>>>(partial, blin, (float*)d_out);
}

// Round 4
// 7632.164 us; speedup vs baseline: 5.6182x; 2.3363x over previous
//
#include <hip/hip_runtime.h>

#define T_STEPS 2048
#define BATCH   256
#define HID     512
#define NG      16   // gate-slice blocks per batch group (h-cols 512/NG = 32 each)
#define NB      16   // batch groups (rows 256/NB = 16 each)

typedef _Float16 half8 __attribute__((ext_vector_type(8)));
typedef _Float16 half2v __attribute__((ext_vector_type(2)));
typedef float f32x4 __attribute__((ext_vector_type(4)));
typedef int int4v __attribute__((ext_vector_type(4)));

__device__ __forceinline__ float sigmoid_f(float v) {
    return 1.f / (1.f + __expf(-v));
}
__device__ __forceinline__ float tanh_f(float v) {
    float a = fabsf(v);
    float e = __expf(2.f * a);
    float r = 1.f - 2.f / (e + 1.f);
    return copysignf(r, v);
}

// grid = 256 blocks (g = blockIdx&15 batch group, j = blockIdx>>4 gate slice)
// block = 256 threads = 4 waves; wave w owns gate type w (i,f,g,o), cols 0..31 of slice
// Cross-block protocol: h + flags move via sc0|sc1 (L1/L2-bypass, MALL-coherent)
// accesses only. h loads are line-granular dwordx4 (inline asm); flags are one
// reused dword per block with monotonically increasing step values.
__global__ __launch_bounds__(256, 1) void lstm_persistent(
    const float* __restrict__ x,     // (T,B)
    const float* __restrict__ Wih,   // (4H,1)
    const float* __restrict__ Whh,   // (4H,H)
    const float* __restrict__ bih,   // (4H)
    const float* __restrict__ bhh,   // (4H)
    const float* __restrict__ Wlin,  // (1,H)
    _Float16* __restrict__ hbuf,     // [2][B][H] fp16
    unsigned*  __restrict__ flags,   // [NB][NG]  (value = last published step + 1)
    float* __restrict__ partial)     // [NG][B]
{
    const int tid  = threadIdx.x;
    const int g    = blockIdx.x & 15;   // batch group
    const int j    = blockIdx.x >> 4;   // gate slice
    const int wave = tid >> 6;          // gate type 0..3
    const int lane = tid & 63;
    const int quad = lane >> 4;
    const int ln16 = lane & 15;

    __shared__ float lds_gates[4][16][32];
    __shared__ float lds_wx[4][32];
    __shared__ float lds_bias[4][32];

    // ---- stationary weights: fp16 MFMA B-fragments in registers ----
    // B[k][n] = Whh[gate_row(n)][k]; lane holds n=ln16, k = quad*8 + e (+32*ks)
    half8 bf0[16], bf1[16];
    {
        const float* wr0 = Whh + (size_t)(wave * 512 + j * 32 + ln16) * HID;
        const float* wr1 = Whh + (size_t)(wave * 512 + j * 32 + 16 + ln16) * HID;
        #pragma unroll
        for (int ks = 0; ks < 16; ++ks) {
            int k0 = ks * 32 + quad * 8;
            half8 v0, v1;
            #pragma unroll
            for (int e = 0; e < 8; ++e) {
                v0[e] = (_Float16)wr0[k0 + e];
                v1[e] = (_Float16)wr1[k0 + e];
            }
            bf0[ks] = v0;
            bf1[ks] = v1;
        }
    }
    if (tid < 128) {
        int gt = tid >> 5, c = tid & 31;
        int grow = gt * 512 + j * 32 + c;
        lds_wx[gt][c]   = Wih[grow];
        lds_bias[gt][c] = bih[grow] + bhh[grow];
    }
    __syncthreads();

    const int row_e = tid >> 4;          // epilogue row 0..15
    const int cp    = (tid & 15) * 2;    // epilogue col pair 0,2,..,30
    float c0 = 0.f, c1 = 0.f;            // cell state (fp32, register-resident)
    float hl0 = 0.f, hl1 = 0.f;          // last h values (fp32)
    bool  dead = false;                  // sticky bailout (avoid unbounded hang)

    float x_cur = x[(size_t)g * 16 + row_e];   // x for t=0

    for (int t = 0; t < T_STEPS; ++t) {
        // ---- wait for peers' h of step t-1: relaxed agent polls on reused slots ----
        if (t > 0 && !dead) {
            const unsigned* fl = flags + g * NG + ln16;
            unsigned it = 0;
            for (;;) {
                unsigned v = __hip_atomic_load(fl, __ATOMIC_RELAXED, __HIP_MEMORY_SCOPE_AGENT);
                if (__ballot(v >= (unsigned)t) == ~0ull) break;
                if (++it > 200000000u) { dead = true; break; }
            }
        }

        // ---- h fragments: 16 line-granular sc0|sc1 dwordx4 loads (bypass L1/L2) ----
        unsigned long long haddr = (unsigned long long)(
            (const char*)(hbuf + (size_t)(t & 1) * (BATCH * HID)
                               + (size_t)(g * 16 + ln16) * HID) + quad * 16);
        int4v h0,h1,h2,h3,h4,h5,h6,h7,h8,h9,h10,h11,h12,h13,h14,h15;
        asm volatile(
            "global_load_dwordx4 %0,  %16, off sc0 sc1\n\t"
            "global_load_dwordx4 %1,  %16, off offset:64 sc0 sc1\n\t"
            "global_load_dwordx4 %2,  %16, off offset:128 sc0 sc1\n\t"
            "global_load_dwordx4 %3,  %16, off offset:192 sc0 sc1\n\t"
            "global_load_dwordx4 %4,  %16, off offset:256 sc0 sc1\n\t"
            "global_load_dwordx4 %5,  %16, off offset:320 sc0 sc1\n\t"
            "global_load_dwordx4 %6,  %16, off offset:384 sc0 sc1\n\t"
            "global_load_dwordx4 %7,  %16, off offset:448 sc0 sc1\n\t"
            "global_load_dwordx4 %8,  %16, off offset:512 sc0 sc1\n\t"
            "global_load_dwordx4 %9,  %16, off offset:576 sc0 sc1\n\t"
            "global_load_dwordx4 %10, %16, off offset:640 sc0 sc1\n\t"
            "global_load_dwordx4 %11, %16, off offset:704 sc0 sc1\n\t"
            "global_load_dwordx4 %12, %16, off offset:768 sc0 sc1\n\t"
            "global_load_dwordx4 %13, %16, off offset:832 sc0 sc1\n\t"
            "global_load_dwordx4 %14, %16, off offset:896 sc0 sc1\n\t"
            "global_load_dwordx4 %15, %16, off offset:960 sc0 sc1\n\t"
            "s_waitcnt vmcnt(0)"
            : "=&v"(h0), "=&v"(h1), "=&v"(h2), "=&v"(h3),
              "=&v"(h4), "=&v"(h5), "=&v"(h6), "=&v"(h7),
              "=&v"(h8), "=&v"(h9), "=&v"(h10), "=&v"(h11),
              "=&v"(h12), "=&v"(h13), "=&v"(h14), "=&v"(h15)
            : "v"(haddr));

        // prefetch x for next step (overlaps MFMA + epilogue + store drain)
        float x_next = x[(size_t)(t + 1 < T_STEPS ? t + 1 : t) * BATCH + g * 16 + row_e];

        f32x4 a0e = {0.f,0.f,0.f,0.f}, a0o = {0.f,0.f,0.f,0.f};
        f32x4 a1e = {0.f,0.f,0.f,0.f}, a1o = {0.f,0.f,0.f,0.f};
        #define MF(idx, hx) { half8 af = __builtin_bit_cast(half8, hx);                        \
            if ((idx) & 1) {                                                                    \
                a0o = __builtin_amdgcn_mfma_f32_16x16x32_f16(af, bf0[idx], a0o, 0, 0, 0);       \
                a1o = __builtin_amdgcn_mfma_f32_16x16x32_f16(af, bf1[idx], a1o, 0, 0, 0);       \
            } else {                                                                            \
                a0e = __builtin_amdgcn_mfma_f32_16x16x32_f16(af, bf0[idx], a0e, 0, 0, 0);       \
                a1e = __builtin_amdgcn_mfma_f32_16x16x32_f16(af, bf1[idx], a1e, 0, 0, 0);       \
            } }
        MF(0,h0)  MF(1,h1)  MF(2,h2)   MF(3,h3)
        MF(4,h4)  MF(5,h5)  MF(6,h6)   MF(7,h7)
        MF(8,h8)  MF(9,h9)  MF(10,h10) MF(11,h11)
        MF(12,h12) MF(13,h13) MF(14,h14) MF(15,h15)
        #undef MF
        f32x4 acc0 = a0e + a0o;
        f32x4 acc1 = a1e + a1o;
        // C layout: col = ln16, row = quad*4 + r
        #pragma unroll
        for (int r = 0; r < 4; ++r) {
            lds_gates[wave][quad * 4 + r][ln16]      = acc0[r];
            lds_gates[wave][quad * 4 + r][16 + ln16] = acc1[r];
        }
        __syncthreads();

        // ---- epilogue: thread -> (row_e, cols cp,cp+1); c in regs; h -> global fp16 ----
        const float xin = x_cur;
        float hv0, hv1;
        {
            float gi = lds_gates[0][row_e][cp]     + xin * lds_wx[0][cp]     + lds_bias[0][cp];
            float gf = lds_gates[1][row_e][cp]     + xin * lds_wx[1][cp]     + lds_bias[1][cp];
            float gg = lds_gates[2][row_e][cp]     + xin * lds_wx[2][cp]     + lds_bias[2][cp];
            float go = lds_gates[3][row_e][cp]     + xin * lds_wx[3][cp]     + lds_bias[3][cp];
            float iv = sigmoid_f(gi), fv = sigmoid_f(gf), gv = tanh_f(gg), ov = sigmoid_f(go);
            c0 = fv * c0 + iv * gv;
            hv0 = ov * tanh_f(c0);
        }
        {
            float gi = lds_gates[0][row_e][cp + 1] + xin * lds_wx[0][cp + 1] + lds_bias[0][cp + 1];
            float gf = lds_gates[1][row_e][cp + 1] + xin * lds_wx[1][cp + 1] + lds_bias[1][cp + 1];
            float gg = lds_gates[2][row_e][cp + 1] + xin * lds_wx[2][cp + 1] + lds_bias[2][cp + 1];
            float go = lds_gates[3][row_e][cp + 1] + xin * lds_wx[3][cp + 1] + lds_bias[3][cp + 1];
            float iv = sigmoid_f(gi), fv = sigmoid_f(gf), gv = tanh_f(gg), ov = sigmoid_f(go);
            c1 = fv * c1 + iv * gv;
            hv1 = ov * tanh_f(c1);
        }
        hl0 = hv0; hl1 = hv1;
        half2v hh;
        hh[0] = (_Float16)hv0;
        hh[1] = (_Float16)hv1;
        unsigned hbits = __builtin_bit_cast(unsigned, hh);
        // agent-scope store: straight to the coherence point, never dirty in L2
        __hip_atomic_store(
            (unsigned*)(hbuf + (size_t)((t + 1) & 1) * (BATCH * HID)
                             + (size_t)(g * 16 + row_e) * HID + j * 32 + cp),
            hbits, __ATOMIC_RELAXED, __HIP_MEMORY_SCOPE_AGENT);

        __syncthreads();  // s_waitcnt vmcnt(0): all h stores are at the MALL
        if (tid == 0) {
            __hip_atomic_store(flags + g * NG + j, (unsigned)(t + 1),
                               __ATOMIC_RELAXED, __HIP_MEMORY_SCOPE_AGENT);
        }
        x_cur = x_next;
    }

    // ---- partial output: sum over this block's 32 h-cols per row ----
    float p = hl0 * Wlin[j * 32 + cp] + hl1 * Wlin[j * 32 + cp + 1];
    #pragma unroll
    for (int off = 8; off; off >>= 1) p += __shfl_down(p, off, 16);
    if ((tid & 15) == 0) partial[(size_t)j * BATCH + g * 16 + row_e] = p;
}

__global__ void lstm_finalize(const float* __restrict__ partial,
                              const float* __restrict__ blin,
                              float* __restrict__ out)
{
    int b = threadIdx.x;
    float s = blin[0];
    #pragma unroll
    for (int j = 0; j < NG; ++j) s += partial[(size_t)j * BATCH + b];
    out[b] = s;
}

extern "C" void kernel_launch(void* const* d_in, const int* in_sizes, int n_in,
                              void* d_out, int out_size, void* d_ws, size_t ws_size,
                              hipStream_t stream) {
    const float* x    = (const float*)d_in[0];
    const float* Wih  = (const float*)d_in[1];
    const float* Whh  = (const float*)d_in[2];
    const float* bih  = (const float*)d_in[3];
    const float* bhh  = (const float*)d_in[4];
    const float* Wlin = (const float*)d_in[5];
    const float* blin = (const float*)d_in[6];

    char* ws = (char*)d_ws;
    _Float16* hbuf   = (_Float16*)ws;                                  // 2*256*512*2 = 512 KB
    unsigned* flags  = (unsigned*)(ws + (512 << 10));                  // NB*NG*4 = 1 KB
    float*    partial = (float*)(ws + (512 << 10) + (2 << 20));        // 16 KB

    // zero h(t=-1) buffer (buf0) and the reused flag slots
    hipMemsetAsync(hbuf, 0, (size_t)BATCH * HID * sizeof(_Float16), stream);
    hipMemsetAsync(flags, 0, (size_t)NB * NG * sizeof(unsigned), stream);

    lstm_persistent<<<dim3(256), dim3(256), 0, stream>>>(
        x, Wih, Whh, bih, bhh, Wlin, hbuf, flags, partial);
    lstm_finalize<<<dim3(1), dim3(256), 0, stream>>>(partial, blin, (float*)d_out);
}

// Round 6
// 6081.174 us; speedup vs baseline: 7.0511x; 1.2550x over previous
//
#include <hip/hip_runtime.h>

#define T_STEPS 2048
#define BATCH   256
#define HID     512
#define NG      16   // gate-slice blocks per batch group (h-cols 512/NG = 32 each)
#define NB      16   // batch groups (rows 256/NB = 16 each)

typedef _Float16 half8 __attribute__((ext_vector_type(8)));
typedef _Float16 half2v __attribute__((ext_vector_type(2)));
typedef float f32x4 __attribute__((ext_vector_type(4)));
typedef int int4v __attribute__((ext_vector_type(4)));

__device__ __forceinline__ float sigmoid_f(float v) {
    return 1.f / (1.f + __expf(-v));
}
__device__ __forceinline__ float tanh_f(float v) {
    float a = fabsf(v);
    float e = __expf(2.f * a);
    float r = 1.f - 2.f / (e + 1.f);
    return copysignf(r, v);
}

// grid = 256 blocks (g = blockIdx&15 batch group, j = blockIdx>>4 gate slice)
// block = 256 threads = 4 waves.
// K-split across waves: wave w holds W_hh B-fragments for ALL 4 gates over
// k in [128w, 128w+128) (same 128 VGPRs as the old gate-split), loads only its
// own 4 disjoint 16B A-chunks per lane (64 cache lines/block/step instead of
// 1024), computes 4-gate partial sums, and the existing LDS gates round-trip
// doubles as the cross-wave K-reduction — no extra barrier.
// Cross-block protocol (round-4-proven): h + flags via sc0|sc1 (MALL-coherent)
// accesses; per-block monotone flag published by tid 0 after a barrier that
// drains every wave's h stores.
__global__ __launch_bounds__(256, 1) void lstm_persistent(
    const float* __restrict__ x,     // (T,B)
    const float* __restrict__ Wih,   // (4H,1)
    const float* __restrict__ Whh,   // (4H,H)
    const float* __restrict__ bih,   // (4H)
    const float* __restrict__ bhh,   // (4H)
    const float* __restrict__ Wlin,  // (1,H)
    _Float16* __restrict__ hbuf,     // [2][B][H] fp16
    unsigned*  __restrict__ flags,   // [NB][NG] (value = last published step + 1)
    float* __restrict__ partial)     // [NG][B]
{
    const int tid  = threadIdx.x;
    const int g    = blockIdx.x & 15;   // batch group
    const int j    = blockIdx.x >> 4;   // gate slice
    const int wave = tid >> 6;          // k-slice owner: k in [128*wave, 128*wave+128)
    const int lane = tid & 63;
    const int quad = lane >> 4;
    const int ln16 = lane & 15;

    // lds_part[w][gate][row][col(+pad)] : per-wave partial gate sums
    __shared__ float lds_part[4][4][16][33];
    __shared__ float lds_wx[4][32];
    __shared__ float lds_bias[4][32];

    // ---- stationary weights: fp16 MFMA B-fragments in registers ----
    // bf[gate][colhalf][ksl]: B[k][n] = Whh[gate*512 + j*32 + colhalf*16 + ln16][k],
    // k = (wave*4 + ksl)*32 + quad*8 + e
    half8 bf[4][2][4];
    #pragma unroll
    for (int gt = 0; gt < 4; ++gt) {
        #pragma unroll
        for (int ch = 0; ch < 2; ++ch) {
            const float* wr = Whh + (size_t)(gt * 512 + j * 32 + ch * 16 + ln16) * HID;
            #pragma unroll
            for (int ksl = 0; ksl < 4; ++ksl) {
                int k0 = (wave * 4 + ksl) * 32 + quad * 8;
                half8 v;
                #pragma unroll
                for (int e = 0; e < 8; ++e) v[e] = (_Float16)wr[k0 + e];
                bf[gt][ch][ksl] = v;
            }
        }
    }
    if (tid < 128) {
        int gt = tid >> 5, c = tid & 31;
        int grow = gt * 512 + j * 32 + c;
        lds_wx[gt][c]   = Wih[grow];
        lds_bias[gt][c] = bih[grow] + bhh[grow];
    }
    __syncthreads();

    const int row_e = tid >> 4;          // epilogue row 0..15
    const int cp    = (tid & 15) * 2;    // epilogue col pair 0,2,..,30
    float c0 = 0.f, c1 = 0.f;            // cell state (fp32, register-resident)
    float hl0 = 0.f, hl1 = 0.f;          // last h values (fp32)
    bool  dead = false;                  // sticky bailout

    float x_cur = x[(size_t)g * 16 + row_e];   // x for t=0

    for (int t = 0; t < T_STEPS; ++t) {
        // ---- wait for peers' h of step t-1: relaxed agent polls on reused slots ----
        if (t > 0 && !dead) {
            const unsigned* fl = flags + g * NG + ln16;
            unsigned it = 0;
            for (;;) {
                unsigned v = __hip_atomic_load(fl, __ATOMIC_RELAXED, __HIP_MEMORY_SCOPE_AGENT);
                if (__ballot(v >= (unsigned)t) == ~0ull) break;
                if (++it > 200000000u) { dead = true; break; }
            }
        }

        // ---- this wave's disjoint A-chunk: 4 line-granular sc0|sc1 dwordx4 loads ----
        // lane (quad, ln16) reads row g*16+ln16, bytes [wave*256 + quad*16 + ksl*64]
        unsigned long long haddr = (unsigned long long)(
            (const char*)(hbuf + (size_t)(t & 1) * (BATCH * HID)
                               + (size_t)(g * 16 + ln16) * HID)
            + wave * 256 + quad * 16);
        int4v h0, h1, h2, h3;
        asm volatile(
            "global_load_dwordx4 %0, %4, off sc0 sc1\n\t"
            "global_load_dwordx4 %1, %4, off offset:64 sc0 sc1\n\t"
            "global_load_dwordx4 %2, %4, off offset:128 sc0 sc1\n\t"
            "global_load_dwordx4 %3, %4, off offset:192 sc0 sc1\n\t"
            "s_waitcnt vmcnt(0)"
            : "=&v"(h0), "=&v"(h1), "=&v"(h2), "=&v"(h3)
            : "v"(haddr) : "memory");

        // prefetch x for next step (overlaps MFMA + epilogue + store drain)
        float x_next = x[(size_t)(t + 1 < T_STEPS ? t + 1 : t) * BATCH + g * 16 + row_e];

        // ---- 32 MFMAs: 4 gates x 2 col-halves x 4 k-sub-slices (partial sums) ----
        f32x4 acc[4][2];
        #pragma unroll
        for (int gt = 0; gt < 4; ++gt) {
            acc[gt][0] = (f32x4){0.f, 0.f, 0.f, 0.f};
            acc[gt][1] = (f32x4){0.f, 0.f, 0.f, 0.f};
        }
        #define KSTEP(ksl, hx) {                                                      \
            half8 af = __builtin_bit_cast(half8, hx);                                 \
            _Pragma("unroll")                                                         \
            for (int gt = 0; gt < 4; ++gt) {                                          \
                acc[gt][0] = __builtin_amdgcn_mfma_f32_16x16x32_f16(af, bf[gt][0][ksl], acc[gt][0], 0, 0, 0); \
                acc[gt][1] = __builtin_amdgcn_mfma_f32_16x16x32_f16(af, bf[gt][1][ksl], acc[gt][1], 0, 0, 0); \
            } }
        KSTEP(0, h0) KSTEP(1, h1) KSTEP(2, h2) KSTEP(3, h3)
        #undef KSTEP

        // C layout: col = ln16, row = quad*4 + r  -> per-wave partials to LDS
        #pragma unroll
        for (int gt = 0; gt < 4; ++gt) {
            #pragma unroll
            for (int r = 0; r < 4; ++r) {
                lds_part[wave][gt][quad * 4 + r][ln16]      = acc[gt][0][r];
                lds_part[wave][gt][quad * 4 + r][16 + ln16] = acc[gt][1][r];
            }
        }
        __syncthreads();

        // ---- epilogue: reduce 4 wave-partials, activations, c/h update ----
        const float xin = x_cur;
        float hv0, hv1;
        {
            float gi = lds_part[0][0][row_e][cp] + lds_part[1][0][row_e][cp]
                     + lds_part[2][0][row_e][cp] + lds_part[3][0][row_e][cp]
                     + xin * lds_wx[0][cp] + lds_bias[0][cp];
            float gf = lds_part[0][1][row_e][cp] + lds_part[1][1][row_e][cp]
                     + lds_part[2][1][row_e][cp] + lds_part[3][1][row_e][cp]
                     + xin * lds_wx[1][cp] + lds_bias[1][cp];
            float gg = lds_part[0][2][row_e][cp] + lds_part[1][2][row_e][cp]
                     + lds_part[2][2][row_e][cp] + lds_part[3][2][row_e][cp]
                     + xin * lds_wx[2][cp] + lds_bias[2][cp];
            float go = lds_part[0][3][row_e][cp] + lds_part[1][3][row_e][cp]
                     + lds_part[2][3][row_e][cp] + lds_part[3][3][row_e][cp]
                     + xin * lds_wx[3][cp] + lds_bias[3][cp];
            float iv = sigmoid_f(gi), fv = sigmoid_f(gf), gv = tanh_f(gg), ov = sigmoid_f(go);
            c0 = fv * c0 + iv * gv;
            hv0 = ov * tanh_f(c0);
        }
        {
            int cq = cp + 1;
            float gi = lds_part[0][0][row_e][cq] + lds_part[1][0][row_e][cq]
                     + lds_part[2][0][row_e][cq] + lds_part[3][0][row_e][cq]
                     + xin * lds_wx[0][cq] + lds_bias[0][cq];
            float gf = lds_part[0][1][row_e][cq] + lds_part[1][1][row_e][cq]
                     + lds_part[2][1][row_e][cq] + lds_part[3][1][row_e][cq]
                     + xin * lds_wx[1][cq] + lds_bias[1][cq];
            float gg = lds_part[0][2][row_e][cq] + lds_part[1][2][row_e][cq]
                     + lds_part[2][2][row_e][cq] + lds_part[3][2][row_e][cq]
                     + xin * lds_wx[2][cq] + lds_bias[2][cq];
            float go = lds_part[0][3][row_e][cq] + lds_part[1][3][row_e][cq]
                     + lds_part[2][3][row_e][cq] + lds_part[3][3][row_e][cq]
                     + xin * lds_wx[3][cq] + lds_bias[3][cq];
            float iv = sigmoid_f(gi), fv = sigmoid_f(gf), gv = tanh_f(gg), ov = sigmoid_f(go);
            c1 = fv * c1 + iv * gv;
            hv1 = ov * tanh_f(c1);
        }
        hl0 = hv0; hl1 = hv1;
        half2v hh;
        hh[0] = (_Float16)hv0;
        hh[1] = (_Float16)hv1;
        unsigned hbits = __builtin_bit_cast(unsigned, hh);
        // agent-scope store: straight to the coherence point, never dirty in L2
        __hip_atomic_store(
            (unsigned*)(hbuf + (size_t)((t + 1) & 1) * (BATCH * HID)
                             + (size_t)(g * 16 + row_e) * HID + j * 32 + cp),
            hbits, __ATOMIC_RELAXED, __HIP_MEMORY_SCOPE_AGENT);

        asm volatile("s_waitcnt vmcnt(0)" ::: "memory");
        __syncthreads();  // every wave's h stores drained before publish
        if (tid == 0) {
            __hip_atomic_store(flags + g * NG + j, (unsigned)(t + 1),
                               __ATOMIC_RELAXED, __HIP_MEMORY_SCOPE_AGENT);
        }
        x_cur = x_next;
    }

    // ---- partial output: sum over this block's 32 h-cols per row ----
    float p = hl0 * Wlin[j * 32 + cp] + hl1 * Wlin[j * 32 + cp + 1];
    #pragma unroll
    for (int off = 8; off; off >>= 1) p += __shfl_down(p, off, 16);
    if ((tid & 15) == 0) partial[(size_t)j * BATCH + g * 16 + row_e] = p;
}

__global__ void lstm_finalize(const float* __restrict__ partial,
                              const float* __restrict__ blin,
                              float* __restrict__ out)
{
    int b = threadIdx.x;
    float s = blin[0];
    #pragma unroll
    for (int jj = 0; jj < NG; ++jj) s += partial[(size_t)jj * BATCH + b];
    out[b] = s;
}

extern "C" void kernel_launch(void* const* d_in, const int* in_sizes, int n_in,
                              void* d_out, int out_size, void* d_ws, size_t ws_size,
                              hipStream_t stream) {
    const float* x    = (const float*)d_in[0];
    const float* Wih  = (const float*)d_in[1];
    const float* Whh  = (const float*)d_in[2];
    const float* bih  = (const float*)d_in[3];
    const float* bhh  = (const float*)d_in[4];
    const float* Wlin = (const float*)d_in[5];
    const float* blin = (const float*)d_in[6];

    char* ws = (char*)d_ws;
    _Float16* hbuf    = (_Float16*)ws;                         // 512 KB
    unsigned* flags   = (unsigned*)(ws + (512 << 10));         // 16*16*4 = 1 KB
    float*    partial = (float*)(ws + (520 << 10));            // 16 KB

    // zero h(t=-1) buffer (buf0) and the reused flag slots
    hipMemsetAsync(hbuf, 0, (size_t)BATCH * HID * sizeof(_Float16), stream);
    hipMemsetAsync(flags, 0, (size_t)NB * NG * sizeof(unsigned), stream);

    lstm_persistent<<<dim3(256), dim3(256), 0, stream>>>(
        x, Wih, Whh, bih, bhh, Wlin, hbuf, flags, partial);
    lstm_finalize<<<dim3(1), dim3(256), 0, stream>>>(partial, blin, (float*)d_out);
}

// Round 7
// 4382.013 us; speedup vs baseline: 9.7852x; 1.3878x over previous
//
#include <hip/hip_runtime.h>

#define T_STEPS 2048
#define BATCH   256
#define HID     512
#define NG      16   // gate-slice blocks per batch group (h-cols 512/NG = 32 each)
#define NB      16   // batch groups (rows 256/NB = 16 each)
#define RING    6    // h ring slots (sentinel dataflow protocol)
#define SENT    0x3C3C3C3C  // fp16 pair (1.0586,1.0586) — unreachable: |h|<=1.0 => halves <= 0x3C00

typedef _Float16 half8 __attribute__((ext_vector_type(8)));
typedef float f32x4 __attribute__((ext_vector_type(4)));
typedef int int4v __attribute__((ext_vector_type(4)));

__device__ __forceinline__ float sigmoid_f(float v) {
    return 1.f / (1.f + __expf(-v));
}
__device__ __forceinline__ float tanh_f(float v) {
    float a = fabsf(v);
    float e = __expf(2.f * a);
    float r = 1.f - 2.f / (e + 1.f);
    return copysignf(r, v);
}

// grid = 256 blocks (g = blockIdx&15 batch group, j = blockIdx>>4 gate slice)
// block = 256 threads = 4 waves, K-split (wave w owns k in [128w,128w+128)).
//
// Sentinel-dataflow sync (no flags, no publish barrier, no flag->data trip):
//  - h lives in a 6-slot ring; slot for step t input = t%6.
//  - Producers store h via sc0|sc1 (MALL-coherent); consumers poll their own
//    A-fragment lines until all dwords != SENT — the poll IS the data load.
//  - Consumed slot (t-1)%6 is reset to SENT after the mid-step barrier (the
//    barrier proves, via this block's 4 waves having collectively observed all
//    16 peer outputs of step t-1, that every peer wave finished reading it).
//  - End-of-step s_waitcnt vmcnt(0) makes resets/stores visible before this
//    block's NEXT store is issued -> inductively visible before any peer's
//    re-poll of that slot 5 steps later. WAR on slot rewrite follows from the
//    same dataflow chain (poll success at t => peers passed barrier t-1 =>
//    their reads of older slots retired).
__global__ __launch_bounds__(256, 1) void lstm_persistent(
    const float* __restrict__ x,     // (T,B)
    const float* __restrict__ Wih,   // (4H,1)
    const float* __restrict__ Whh,   // (4H,H)
    const float* __restrict__ bih,   // (4H)
    const float* __restrict__ bhh,   // (4H)
    const float* __restrict__ Wlin,  // (1,H)
    _Float16* __restrict__ hbuf,     // [RING][B][H] fp16
    float* __restrict__ partial)     // [NG][B]
{
    const int tid  = threadIdx.x;
    const int g    = blockIdx.x & 15;   // batch group
    const int j    = blockIdx.x >> 4;   // gate slice
    const int wave = tid >> 6;          // k-slice owner: k in [128*wave, 128*wave+128)
    const int lane = tid & 63;
    const int quad = lane >> 4;
    const int ln16 = lane & 15;

    // pad 34 (even): bank = (2*row + col) % 32 -> <=2-way on writes (free),
    // b64 reads ~4-way worst. Double-buffered (t&1): lets us run ONE barrier/step.
    __shared__ float lds_part[2][4][4][16][34];

    // ---- stationary weights: fp16 MFMA B-fragments in registers ----
    // bf[gate][colhalf][ksl]: B[k][n] = Whh[gate*512 + j*32 + colhalf*16 + ln16][k],
    // k = (wave*4 + ksl)*32 + quad*8 + e
    half8 bf[4][2][4];
    #pragma unroll
    for (int gt = 0; gt < 4; ++gt) {
        #pragma unroll
        for (int ch = 0; ch < 2; ++ch) {
            const float* wr = Whh + (size_t)(gt * 512 + j * 32 + ch * 16 + ln16) * HID;
            #pragma unroll
            for (int ksl = 0; ksl < 4; ++ksl) {
                int k0 = (wave * 4 + ksl) * 32 + quad * 8;
                half8 v;
                #pragma unroll
                for (int e = 0; e < 8; ++e) v[e] = (_Float16)wr[k0 + e];
                bf[gt][ch][ksl] = v;
            }
        }
    }

    const int row_e = tid >> 4;          // epilogue row 0..15
    const int cp    = (tid & 15) * 2;    // epilogue col pair 0,2,..,30

    // per-thread epilogue constants in registers (was LDS)
    float wxA[4], wxB[4], bsA[4], bsB[4];
    #pragma unroll
    for (int gt = 0; gt < 4; ++gt) {
        int r0 = gt * 512 + j * 32 + cp;
        wxA[gt] = Wih[r0];
        wxB[gt] = Wih[r0 + 1];
        bsA[gt] = bih[r0] + bhh[r0];
        bsB[gt] = bih[r0 + 1] + bhh[r0 + 1];
    }

    float c0 = 0.f, c1 = 0.f;            // cell state (fp32, register-resident)
    float hl0 = 0.f, hl1 = 0.f;          // last h values (fp32)
    bool  dead = false;                  // sticky bailout

    float x_cur = x[(size_t)g * 16 + row_e];   // x for t=0

    int s_in = 0, s_out = 1, s_rst = 5;

    for (int t = 0; t < T_STEPS; ++t) {
        // ---- poll own A-fragment lines of slot s_in (the poll IS the load) ----
        unsigned long long haddr = (unsigned long long)(
            (const char*)hbuf
            + ((size_t)s_in * (BATCH * HID) + (size_t)(g * 16 + ln16) * HID) * 2
            + wave * 256 + quad * 16);
        int4v h0, h1, h2, h3;
        {
            unsigned it = 0;
            for (;;) {
                asm volatile(
                    "global_load_dwordx4 %0, %4, off sc0 sc1\n\t"
                    "global_load_dwordx4 %1, %4, off offset:64 sc0 sc1\n\t"
                    "global_load_dwordx4 %2, %4, off offset:128 sc0 sc1\n\t"
                    "global_load_dwordx4 %3, %4, off offset:192 sc0 sc1\n\t"
                    "s_waitcnt vmcnt(0)"
                    : "=&v"(h0), "=&v"(h1), "=&v"(h2), "=&v"(h3)
                    : "v"(haddr) : "memory");
                bool ok = true;
                #pragma unroll
                for (int e = 0; e < 4; ++e) {
                    ok = ok && (h0[e] != (int)SENT) && (h1[e] != (int)SENT)
                            && (h2[e] != (int)SENT) && (h3[e] != (int)SENT);
                }
                if (__ballot(ok) == ~0ull || dead) break;
                if (++it > 100000000u) { dead = true; break; }
            }
        }

        // prefetch x for next step (overlaps MFMA + epilogue)
        float x_next = x[(size_t)(t + 1 < T_STEPS ? t + 1 : t) * BATCH + g * 16 + row_e];

        // ---- 32 MFMAs: 4 gates x 2 col-halves x 4 k-sub-slices (partial sums) ----
        f32x4 acc[4][2];
        #pragma unroll
        for (int gt = 0; gt < 4; ++gt) {
            acc[gt][0] = (f32x4){0.f, 0.f, 0.f, 0.f};
            acc[gt][1] = (f32x4){0.f, 0.f, 0.f, 0.f};
        }
        #define KSTEP(ksl, hx) {                                                      \
            half8 af = __builtin_bit_cast(half8, hx);                                 \
            _Pragma("unroll")                                                         \
            for (int gt = 0; gt < 4; ++gt) {                                          \
                acc[gt][0] = __builtin_amdgcn_mfma_f32_16x16x32_f16(af, bf[gt][0][ksl], acc[gt][0], 0, 0, 0); \
                acc[gt][1] = __builtin_amdgcn_mfma_f32_16x16x32_f16(af, bf[gt][1][ksl], acc[gt][1], 0, 0, 0); \
            } }
        KSTEP(0, h0) KSTEP(1, h1) KSTEP(2, h2) KSTEP(3, h3)
        #undef KSTEP

        // C layout: col = ln16, row = quad*4 + r  -> per-wave partials to LDS
        const int tb = t & 1;
        #pragma unroll
        for (int gt = 0; gt < 4; ++gt) {
            #pragma unroll
            for (int r = 0; r < 4; ++r) {
                lds_part[tb][wave][gt][quad * 4 + r][ln16]      = acc[gt][0][r];
                lds_part[tb][wave][gt][quad * 4 + r][16 + ln16] = acc[gt][1][r];
            }
        }
        __syncthreads();   // the ONLY barrier per step

        // ---- reset consumed slot s_rst (own 1KB region, 1 dword/thread) ----
        {
            unsigned long long radr = (unsigned long long)(
                (char*)hbuf
                + ((size_t)s_rst * (BATCH * HID)
                   + (size_t)(g * 16 + row_e) * HID + j * 32 + cp) * 2);
            unsigned sv = SENT;
            asm volatile("global_store_dword %0, %1, off sc0 sc1"
                         : : "v"(radr), "v"(sv) : "memory");
        }

        // ---- epilogue: reduce 4 wave-partials, activations, c/h update ----
        const float xin = x_cur;
        float sA[4] = {0.f, 0.f, 0.f, 0.f};
        float sB[4] = {0.f, 0.f, 0.f, 0.f};
        #pragma unroll
        for (int w = 0; w < 4; ++w) {
            #pragma unroll
            for (int gt = 0; gt < 4; ++gt) {
                float2 v = *(const float2*)&lds_part[tb][w][gt][row_e][cp];
                sA[gt] += v.x;
                sB[gt] += v.y;
            }
        }
        float hv0, hv1;
        {
            float gi = sA[0] + xin * wxA[0] + bsA[0];
            float gf = sA[1] + xin * wxA[1] + bsA[1];
            float gg = sA[2] + xin * wxA[2] + bsA[2];
            float go = sA[3] + xin * wxA[3] + bsA[3];
            float iv = sigmoid_f(gi), fv = sigmoid_f(gf), gv = tanh_f(gg), ov = sigmoid_f(go);
            c0 = fv * c0 + iv * gv;
            hv0 = ov * tanh_f(c0);
        }
        {
            float gi = sB[0] + xin * wxB[0] + bsB[0];
            float gf = sB[1] + xin * wxB[1] + bsB[1];
            float gg = sB[2] + xin * wxB[2] + bsB[2];
            float go = sB[3] + xin * wxB[3] + bsB[3];
            float iv = sigmoid_f(gi), fv = sigmoid_f(gf), gv = tanh_f(gg), ov = sigmoid_f(go);
            c1 = fv * c1 + iv * gv;
            hv1 = ov * tanh_f(c1);
        }
        hl0 = hv0; hl1 = hv1;

        // ---- store h(t+1) into slot s_out; data store IS the publish ----
        {
            _Float16 p0 = (_Float16)hv0, p1 = (_Float16)hv1;
            unsigned hbits = ((unsigned)__builtin_bit_cast(unsigned short, p1) << 16)
                           |  (unsigned)__builtin_bit_cast(unsigned short, p0);
            unsigned long long sadr = (unsigned long long)(
                (char*)hbuf
                + ((size_t)s_out * (BATCH * HID)
                   + (size_t)(g * 16 + row_e) * HID + j * 32 + cp) * 2);
            asm volatile("global_store_dword %0, %1, off sc0 sc1"
                         : : "v"(sadr), "v"(hbits) : "memory");
        }
        // end-of-step drain: resets + h store acked before next iteration's
        // stores are issued (visibility induction); overlaps consumers' detect.
        asm volatile("s_waitcnt vmcnt(0)" ::: "memory");

        x_cur = x_next;
        s_rst = s_in;
        s_in  = s_out;
        s_out = (s_out + 1 == RING) ? 0 : s_out + 1;
    }

    // ---- partial output: sum over this block's 32 h-cols per row ----
    float p = hl0 * Wlin[j * 32 + cp] + hl1 * Wlin[j * 32 + cp + 1];
    #pragma unroll
    for (int off = 8; off; off >>= 1) p += __shfl_down(p, off, 16);
    if ((tid & 15) == 0) partial[(size_t)j * BATCH + g * 16 + row_e] = p;
}

__global__ void lstm_finalize(const float* __restrict__ partial,
                              const float* __restrict__ blin,
                              float* __restrict__ out)
{
    int b = threadIdx.x;
    float s = blin[0];
    #pragma unroll
    for (int jj = 0; jj < NG; ++jj) s += partial[(size_t)jj * BATCH + b];
    out[b] = s;
}

extern "C" void kernel_launch(void* const* d_in, const int* in_sizes, int n_in,
                              void* d_out, int out_size, void* d_ws, size_t ws_size,
                              hipStream_t stream) {
    const float* x    = (const float*)d_in[0];
    const float* Wih  = (const float*)d_in[1];
    const float* Whh  = (const float*)d_in[2];
    const float* bih  = (const float*)d_in[3];
    const float* bhh  = (const float*)d_in[4];
    const float* Wlin = (const float*)d_in[5];
    const float* blin = (const float*)d_in[6];

    char* ws = (char*)d_ws;
    _Float16* hbuf    = (_Float16*)ws;                   // RING * 256KB = 1.5 MB
    float*    partial = (float*)(ws + (2 << 20));        // 16 KB

    const size_t slot_bytes = (size_t)BATCH * HID * sizeof(_Float16);  // 256 KB
    // slot 0 = zeros (h(-1)); slots 1..5 = sentinel (0x3C bytes -> 0x3C3C3C3C dwords)
    hipMemsetAsync(hbuf, 0, slot_bytes, stream);
    hipMemsetAsync((char*)hbuf + slot_bytes, 0x3C, (RING - 1) * slot_bytes, stream);

    lstm_persistent<<<dim3(256), dim3(256), 0, stream>>>(
        x, Wih, Whh, bih, bhh, Wlin, hbuf, partial);
    lstm_finalize<<<dim3(1), dim3(256), 0, stream>>>(partial, blin, (float*)d_out);
}